// Round 1
// baseline (159.446 us; speedup 1.0000x reference)
//
#include <hip/hip_runtime.h>

typedef unsigned short ushort_t;
typedef __attribute__((ext_vector_type(8)))  short  short8;
typedef __attribute__((ext_vector_type(8)))  ushort_t ushort8;
typedef __attribute__((ext_vector_type(16))) float  f32x16;

#define HWPX 16384
#define EPSV 0.001f

__device__ __forceinline__ ushort_t f2bf(float f) {
    unsigned u = __builtin_bit_cast(unsigned, f);
    unsigned r = u + 0x7FFFu + ((u >> 16) & 1u);   // round-to-nearest-even
    return (ushort_t)(r >> 16);
}

// ---------------- Pass 1: per-group mean + raw second moments -------------
// grid 512 = n(8) x g(8) x q(8); block 512 (8 waves). Each block: one group's
// channels (32) over a 2048-pixel slice. cov via rank-k MFMA (frag used as A and B).
__global__ __launch_bounds__(512) void k_stats(const float* __restrict__ x,
                                               float* __restrict__ part) {
    int b = blockIdx.x;
    int n = b >> 6, g = (b >> 3) & 7, q = b & 7;
    int t = threadIdx.x, w = t >> 6, l = t & 63;
    int lo = l & 31, hi = l >> 5;

    const float* xg = x + ((size_t)(n * 256 + g * 32 + lo)) * HWPX;
    int pxbase = q * 2048 + w * 256 + hi * 8;

    f32x16 acc = {};
    float sm = 0.f;
    #pragma unroll 4
    for (int it = 0; it < 16; ++it) {
        const float* p = xg + pxbase + it * 16;
        float4 v0 = *(const float4*)p;
        float4 v1 = *(const float4*)(p + 4);
        sm += v0.x + v0.y + v0.z + v0.w + v1.x + v1.y + v1.z + v1.w;
        short8 f;
        f[0] = (short)f2bf(v0.x); f[1] = (short)f2bf(v0.y);
        f[2] = (short)f2bf(v0.z); f[3] = (short)f2bf(v0.w);
        f[4] = (short)f2bf(v1.x); f[5] = (short)f2bf(v1.y);
        f[6] = (short)f2bf(v1.z); f[7] = (short)f2bf(v1.w);
        acc = __builtin_amdgcn_mfma_f32_32x32x16_bf16(f, f, acc, 0, 0, 0);
    }

    __shared__ float redc[8][1024];
    __shared__ float redm[8][64];
    #pragma unroll
    for (int r = 0; r < 16; ++r) redc[w][l * 16 + r] = acc[r];
    redm[w][l] = sm;
    __syncthreads();

    for (int i = t; i < 1024; i += 512) {
        float v = 0.f;
        #pragma unroll
        for (int ww = 0; ww < 8; ++ww) v += redc[ww][i];
        int ll = i >> 4, r = i & 15;
        int row = (r & 3) + 8 * (r >> 2) + 4 * (ll >> 5);   // C/D layout 32x32 (m74/m101)
        int col = ll & 31;
        part[(size_t)b * 1056 + row * 32 + col] = v;
    }
    if (t < 32) {
        float v = 0.f;
        #pragma unroll
        for (int ww = 0; ww < 8; ++ww) v += redm[ww][t] + redm[ww][t + 32];
        part[(size_t)b * 1056 + 1024 + t] = v;
    }
}

// ---------------- Pass 2: reduce, cov, cholesky, L^{-1} -------------------
// grid 64 = n*8+g; block 64 (1 wave).
__global__ __launch_bounds__(64) void k_chol(const float* __restrict__ part,
                                             float* __restrict__ S,
                                             float* __restrict__ meanw) {
    int bg = blockIdx.x;
    int t = threadIdx.x;
    __shared__ float cov[1024];
    __shared__ float sums[32];
    __shared__ float A[32][33];
    __shared__ float Sl[32][33];

    for (int i = t; i < 1024; i += 64) {
        float v = 0.f;
        for (int q = 0; q < 8; ++q) v += part[(size_t)(bg * 8 + q) * 1056 + i];
        cov[i] = v;
    }
    if (t < 32) {
        float v = 0.f;
        for (int q = 0; q < 8; ++q) v += part[(size_t)(bg * 8 + q) * 1056 + 1024 + t];
        sums[t] = v;
    }
    __syncthreads();

    const float invHW = 1.0f / (float)HWPX;
    for (int i = t; i < 1024; i += 64) {
        int r = i >> 5, c = i & 31;
        float mr = sums[r] * invHW, mc = sums[c] * invHW;
        float cv = (cov[i] * invHW - mr * mc) * (1.0f - EPSV) + ((r == c) ? EPSV : 0.f);
        A[r][c] = cv;
    }
    __syncthreads();

    // right-looking cholesky, lower triangle of A becomes L
    for (int k = 0; k < 32; ++k) {
        if (t == k) A[k][k] = sqrtf(A[k][k]);
        __syncthreads();
        if (t > k && t < 32) A[t][k] = A[t][k] / A[k][k];
        __syncthreads();
        if (t > k && t < 32) {
            float lik = A[t][k];
            for (int j = k + 1; j <= t; ++j) A[t][j] -= lik * A[j][k];
        }
        __syncthreads();
    }

    // S = L^{-1} (forward substitution, one column per lane)
    if (t < 32) {
        int c = t;
        for (int i = 0; i < c; ++i) Sl[i][c] = 0.f;
        Sl[c][c] = 1.0f / A[c][c];
        for (int i = c + 1; i < 32; ++i) {
            float s = 0.f;
            for (int j = c; j < i; ++j) s += A[i][j] * Sl[j][c];
            Sl[i][c] = -s / A[i][i];
        }
    }
    __syncthreads();

    for (int i = t; i < 1024; i += 64) S[(size_t)bg * 1024 + i] = Sl[i >> 5][i & 31];
    if (t < 32) meanw[bg * 32 + t] = sums[t] * invHW;
}

// ---------------- Pass 3: compose M = (conv_w + K^T) * S  -----------------
// grid 64 = n*8+g; block 256 (thread = output row d).
__global__ __launch_bounds__(256) void k_compose(const float* __restrict__ conv_w,
                                                 const float* __restrict__ EK,
                                                 const int* __restrict__ cls_arr,
                                                 const float* __restrict__ S,
                                                 const float* __restrict__ meanw,
                                                 ushort_t* __restrict__ M_bf,
                                                 float* __restrict__ bp) {
    int bid = blockIdx.x;
    int n = bid >> 3, g = bid & 7;
    int d = threadIdx.x;
    __shared__ float Sl[1024];
    __shared__ float ml[32];
    for (int i = d; i < 1024; i += 256) Sl[i] = S[(size_t)bid * 1024 + i];
    if (d < 32) ml[d] = meanw[bid * 32 + d];
    __syncthreads();

    int cls = cls_arr[n];
    float a[32];
    #pragma unroll
    for (int c = 0; c < 32; ++c)
        a[c] = conv_w[d * 256 + g * 32 + c] +
               EK[(size_t)cls * 65536 + (size_t)(g * 32 + c) * 256 + d];

    float bpv = 0.f;
    ushort8 pk[4];
    #pragma unroll
    for (int cp = 0; cp < 32; ++cp) {
        float m = 0.f;
        #pragma unroll
        for (int c = cp; c < 32; ++c) m += a[c] * Sl[c * 32 + cp];  // S lower-tri
        bpv += m * ml[cp];
        pk[cp >> 3][cp & 7] = f2bf(m);
    }
    ushort_t* dst = M_bf + ((size_t)(n * 256 + d)) * 256 + g * 32;
    #pragma unroll
    for (int k = 0; k < 4; ++k) *(ushort8*)(dst + k * 8) = pk[k];
    bp[(size_t)(n * 8 + g) * 256 + d] = bpv;
}

// ---------------- Pass 4: bias' = conv_b + eb - M*mean ---------------------
__global__ __launch_bounds__(256) void k_bias(const float* __restrict__ conv_b,
                                              const float* __restrict__ EB,
                                              const int* __restrict__ cls_arr,
                                              const float* __restrict__ bp,
                                              float* __restrict__ bias) {
    int n = blockIdx.x, d = threadIdx.x;
    int cls = cls_arr[n];
    float v = conv_b[d] + EB[cls * 256 + d];
    #pragma unroll
    for (int g = 0; g < 8; ++g) v -= bp[(size_t)(n * 8 + g) * 256 + d];
    bias[n * 256 + d] = v;
}

// ---------------- Pass 5: out = M_bf * x + bias (no LDS) -------------------
// grid 2048 = n(8) x pxtile(256, 64 px each); block 512 (8 waves, wave = 32 d).
__global__ __launch_bounds__(512) void k_gemm(const float* __restrict__ x,
                                              const ushort_t* __restrict__ M_bf,
                                              const float* __restrict__ bias,
                                              float* __restrict__ out) {
    int bid = blockIdx.x;
    int n = bid >> 8, pt = bid & 255;
    int px0 = pt * 64;
    int t = threadIdx.x, w = t >> 6, l = t & 63, lo = l & 31, hi = l >> 5;
    int dblk = w * 32;

    const ushort_t* Mrow = M_bf + ((size_t)(n * 256 + dblk + lo)) * 256;
    const float* xn = x + (size_t)n * 256 * HWPX;

    f32x16 acc0 = {}, acc1 = {};
    for (int ks = 0; ks < 16; ++ks) {
        int c0 = ks * 16 + hi * 8;
        short8 afrag = *(const short8*)(Mrow + c0);
        const float* xc = xn + (size_t)c0 * HWPX + px0 + lo;
        float b0[8], b1[8];
        #pragma unroll
        for (int bb = 0; bb < 8; ++bb) {
            b0[bb] = xc[(size_t)bb * HWPX];
            b1[bb] = xc[(size_t)bb * HWPX + 32];
        }
        short8 f0, f1;
        #pragma unroll
        for (int bb = 0; bb < 8; ++bb) {
            f0[bb] = (short)f2bf(b0[bb]);
            f1[bb] = (short)f2bf(b1[bb]);
        }
        acc0 = __builtin_amdgcn_mfma_f32_32x32x16_bf16(afrag, f0, acc0, 0, 0, 0);
        acc1 = __builtin_amdgcn_mfma_f32_32x32x16_bf16(afrag, f1, acc1, 0, 0, 0);
    }

    #pragma unroll
    for (int r = 0; r < 16; ++r) {
        int row = dblk + (r & 3) + 8 * (r >> 2) + 4 * hi;   // C/D layout (m74/m101)
        float bs = bias[n * 256 + row];
        size_t o = ((size_t)(n * 256 + row)) * HWPX + px0 + lo;
        out[o] = acc0[r] + bs;
        out[o + 32] = acc1[r] + bs;
    }
}

// ---------------------------------------------------------------------------
extern "C" void kernel_launch(void* const* d_in, const int* in_sizes, int n_in,
                              void* d_out, int out_size, void* d_ws, size_t ws_size,
                              hipStream_t stream) {
    const float* x      = (const float*)d_in[0];
    const int*   cls    = (const int*)d_in[1];
    const float* EK     = (const float*)d_in[2];
    const float* EB     = (const float*)d_in[3];
    const float* conv_w = (const float*)d_in[4];
    const float* conv_b = (const float*)d_in[5];
    float* out = (float*)d_out;

    float* wsf   = (float*)d_ws;
    float* part  = wsf;                  // 512*1056            = 540672 f
    float* S     = wsf + 540672;         // 64*1024             =  65536 f
    float* meanw = wsf + 606208;         // 64*32               =   2048 f
    float* bp    = wsf + 608256;         // 64*256              =  16384 f
    float* bias  = wsf + 624640;         // 8*256               =   2048 f
    ushort_t* M_bf = (ushort_t*)(wsf + 626688);  // 8*256*256 bf16 = 1 MiB

    k_stats  <<<512, 512, 0, stream>>>(x, part);
    k_chol   <<<64,   64, 0, stream>>>(part, S, meanw);
    k_compose<<<64,  256, 0, stream>>>(conv_w, EK, cls, S, meanw, M_bf, bp);
    k_bias   <<<8,   256, 0, stream>>>(conv_b, EB, cls, bp, bias);
    k_gemm   <<<2048, 512, 0, stream>>>(x, M_bf, bias, out);
}